// Round 7
// baseline (310.860 us; speedup 1.0000x reference)
//
#include <hip/hip_runtime.h>

typedef __bf16 bf16x8 __attribute__((ext_vector_type(8)));
typedef float f32x4 __attribute__((ext_vector_type(4)));

__device__ inline float bf2f(unsigned short u) {
    unsigned int x = ((unsigned int)u) << 16;
    return __builtin_bit_cast(float, x);
}
__device__ inline unsigned short f2bf(float f) {
    unsigned int x = __builtin_bit_cast(unsigned int, f);
    x += 0x7fff + ((x >> 16) & 1);   // RNE; inputs finite
    return (unsigned short)(x >> 16);
}

// async global->LDS, 16B per lane; LDS dest = wave-uniform base + lane*16
__device__ __forceinline__ void gl_lds16(const unsigned short* g, unsigned short* l)
{
    __builtin_amdgcn_global_load_lds(
        (const __attribute__((address_space(1))) void*)g,
        (__attribute__((address_space(3))) void*)l, 16, 0, 0);
}

// ---------------------------------------------------------------------------
// Fused prep: blocks [0,2048): x fp32 -> xb bf16 (8 elems/thread).
// Blocks [2048,2816): Wq/Wk/Wv fp32 [k][n] -> wqkvT bf16 [n][k] (64x64 tiles).
// ---------------------------------------------------------------------------
__global__ __launch_bounds__(256)
void prep(const float* __restrict__ x, unsigned short* __restrict__ xb,
          const float* __restrict__ Wq, const float* __restrict__ Wk,
          const float* __restrict__ Wv, unsigned short* __restrict__ wT)
{
    __shared__ unsigned short T[64][72];
    if (blockIdx.x < 2048) {
        const size_t i = ((size_t)blockIdx.x * 256 + threadIdx.x) * 8;
        float4 a = *reinterpret_cast<const float4*>(x + i);
        float4 b = *reinterpret_cast<const float4*>(x + i + 4);
        unsigned short t[8] = { f2bf(a.x), f2bf(a.y), f2bf(a.z), f2bf(a.w),
                                f2bf(b.x), f2bf(b.y), f2bf(b.z), f2bf(b.w) };
        *reinterpret_cast<uint4*>(xb + i) = *reinterpret_cast<uint4*>(t);
        return;
    }
    const int blk = blockIdx.x - 2048;
    const int z = blk >> 8, within = blk & 255;
    const float* W = (z == 0) ? Wq : (z == 1) ? Wk : Wv;
    unsigned short* dstBase = wT + (size_t)z * 1024 * 1024;
    const int k0 = (within >> 4) * 64, n0 = (within & 15) * 64;
    const int r = threadIdx.x >> 2, c0 = (threadIdx.x & 3) * 16;
    const float* src = W + (size_t)(k0 + r) * 1024 + n0 + c0;
    #pragma unroll
    for (int j = 0; j < 16; j += 4) {
        float4 f = *reinterpret_cast<const float4*>(src + j);
        T[r][c0 + j]     = f2bf(f.x);
        T[r][c0 + j + 1] = f2bf(f.y);
        T[r][c0 + j + 2] = f2bf(f.z);
        T[r][c0 + j + 3] = f2bf(f.w);
    }
    __syncthreads();
    unsigned short* dst = dstBase + (size_t)(n0 + r) * 1024 + k0 + c0;
    #pragma unroll
    for (int h = 0; h < 2; ++h) {
        unsigned short t8[8];
        #pragma unroll
        for (int j = 0; j < 8; ++j) t8[j] = T[c0 + h * 8 + j][r];
        *reinterpret_cast<uint4*>(dst + h * 8) = *reinterpret_cast<uint4*>(t8);
    }
}

// ---------------------------------------------------------------------------
// Transpose-convert (Wo): fp32 [k][n] -> bf16 [n][k].
// ---------------------------------------------------------------------------
__global__ __launch_bounds__(256)
void wconv(const float* __restrict__ W, unsigned short* __restrict__ wT)
{
    __shared__ unsigned short T[64][72];
    const int k0 = blockIdx.y * 64, n0 = blockIdx.x * 64;
    const int r = threadIdx.x >> 2, c0 = (threadIdx.x & 3) * 16;
    const float* src = W + (size_t)(k0 + r) * 1024 + n0 + c0;
    #pragma unroll
    for (int j = 0; j < 16; j += 4) {
        float4 f = *reinterpret_cast<const float4*>(src + j);
        T[r][c0 + j]     = f2bf(f.x);
        T[r][c0 + j + 1] = f2bf(f.y);
        T[r][c0 + j + 2] = f2bf(f.z);
        T[r][c0 + j + 3] = f2bf(f.w);
    }
    __syncthreads();
    unsigned short* dst = wT + (size_t)(n0 + r) * 1024 + k0 + c0;
    #pragma unroll
    for (int h = 0; h < 2; ++h) {
        unsigned short t8[8];
        #pragma unroll
        for (int j = 0; j < 8; ++j) t8[j] = T[c0 + h * 8 + j][r];
        *reinterpret_cast<uint4*>(dst + h * 8) = *reinterpret_cast<uint4*>(t8);
    }
}

// ---------------------------------------------------------------------------
// m97-style GEMM: C = A[4096][1024] @ BT[N][1024]^T. 128x128 tile, BK=32,
// unpadded LDS, global_load_lds width-16 staging, 4 waves 2x2, 4x4 mfma.
// MODE 0: QKV routing (q/k normal, v transposed). MODE 2: fp32 out + bias.
// ---------------------------------------------------------------------------
template <int MODE>
__global__ __launch_bounds__(256)
void gemm128(const unsigned short* __restrict__ A,
             const unsigned short* __restrict__ BT,
             void* __restrict__ C0, void* __restrict__ C1,
             void* __restrict__ C2, const float* __restrict__ bias)
{
    __shared__ unsigned short As[128 * 32];
    __shared__ unsigned short Bs[128 * 32];

    const int tid = threadIdx.x;
    const int wave = tid >> 6, lane = tid & 63, quad = lane >> 4, l16 = lane & 15;
    const int wm = wave >> 1, wn = wave & 1;
    const int mBase = blockIdx.y * 128, nBase = blockIdx.x * 128;

    f32x4 acc[4][4] = {};

    const int srow = lane >> 2, sko = (lane & 3) * 8;

    for (int kb = 0; kb < 1024; kb += 32) {
        __syncthreads();
        #pragma unroll
        for (int j = 0; j < 2; ++j) {
            const int seg = wave * 2 + j;
            gl_lds16(A  + (size_t)(mBase + seg * 16 + srow) * 1024 + kb + sko,
                     As + seg * 512);
            gl_lds16(BT + (size_t)(nBase + seg * 16 + srow) * 1024 + kb + sko,
                     Bs + seg * 512);
        }
        __syncthreads();

        bf16x8 af[4], bf[4];
        #pragma unroll
        for (int t = 0; t < 4; ++t) {
            af[t] = *reinterpret_cast<const bf16x8*>(&As[(wm * 64 + t * 16 + l16) * 32 + quad * 8]);
            bf[t] = *reinterpret_cast<const bf16x8*>(&Bs[(wn * 64 + t * 16 + l16) * 32 + quad * 8]);
        }
        #pragma unroll
        for (int ti = 0; ti < 4; ++ti)
            #pragma unroll
            for (int tj = 0; tj < 4; ++tj)
                acc[ti][tj] = __builtin_amdgcn_mfma_f32_16x16x32_bf16(
                    af[ti], bf[tj], acc[ti][tj], 0, 0, 0);
    }

    #pragma unroll
    for (int ti = 0; ti < 4; ++ti) {
        const int row0 = mBase + wm * 64 + ti * 16 + quad * 4;
        #pragma unroll
        for (int tj = 0; tj < 4; ++tj) {
            const int col = nBase + wn * 64 + tj * 16 + l16;
            if constexpr (MODE == 0) {
                if (col < 1024) {
                    unsigned short* qb = (unsigned short*)C0;
                    #pragma unroll
                    for (int i = 0; i < 4; ++i)
                        qb[(size_t)(row0 + i) * 1024 + col] = f2bf(acc[ti][tj][i]);
                } else if (col < 2048) {
                    unsigned short* kb = (unsigned short*)C1;
                    #pragma unroll
                    for (int i = 0; i < 4; ++i)
                        kb[(size_t)(row0 + i) * 1024 + col - 1024] = f2bf(acc[ti][tj][i]);
                } else {
                    unsigned short* vT = (unsigned short*)C2;
                    unsigned short t4[4] = { f2bf(acc[ti][tj][0]), f2bf(acc[ti][tj][1]),
                                             f2bf(acc[ti][tj][2]), f2bf(acc[ti][tj][3]) };
                    *reinterpret_cast<uint2*>(&vT[(size_t)(col - 2048) * 4096 + row0]) =
                        *reinterpret_cast<uint2*>(t4);
                }
            } else {
                float* out = (float*)C0;
                const float ba = bias[col];
                #pragma unroll
                for (int i = 0; i < 4; ++i)
                    out[(size_t)(row0 + i) * 1024 + col] = acc[ti][tj][i] + ba;
            }
        }
    }
}

// ---------------------------------------------------------------------------
// MFMA causal flash attention v3: K-tile 128 (2 barriers per 128 keys).
// 64 q-rows/block, 4 waves (16 q-rows each). No running max (scores
// bounded), masked P=0, per-lane l, one butterfly at end. Causal frag
// skipping on the final tile (nf active 16-key frags, block-uniform).
// ---------------------------------------------------------------------------
#define LDK 72    // Ks row stride (shorts): 36 dwords -> bank rotate 4/row
#define LDV 136   // Vs/Ps row stride: 68 dwords -> bank rotate 4/row

__global__ __launch_bounds__(256)
void attn3(const unsigned short* __restrict__ q,
           const unsigned short* __restrict__ k,
           const unsigned short* __restrict__ vT,
           unsigned short* __restrict__ ctx)
{
    __shared__ unsigned short Ks[128 * LDK]; // [key][d]
    __shared__ unsigned short Vs[64 * LDV];  // [d][key]
    __shared__ unsigned short Ps[64 * LDV];  // [qrow][key]

    const int tid  = threadIdx.x;
    const int wave = tid >> 6, lane = tid & 63, quad = lane >> 4, l16 = lane & 15;
    const int qt = 31 - blockIdx.x;          // longest blocks first
    const int bh = blockIdx.y;
    const int b = bh >> 4, h = bh & 15;
    const int tRowBase = b * 2048;
    const int colBase  = h * 64;
    const int qBase    = qt * 64;

    bf16x8 aq[2];
    {
        const unsigned short* qrow =
            q + (size_t)(tRowBase + qBase + wave * 16 + l16) * 1024 + colBase;
        aq[0] = *reinterpret_cast<const bf16x8*>(qrow + quad * 8);
        aq[1] = *reinterpret_cast<const bf16x8*>(qrow + 32 + quad * 8);
    }

    f32x4 o[4] = {};
    float ls[4] = {};

    const int skr = tid >> 3, sko = (tid & 7) * 8;     // K: rows skr+32m
    const int svr = tid >> 4, svc = (tid & 15) * 8;    // V: rows svr+16m

    uint4 kr[4], vr[4];
    {   // prefetch tile 0
        const size_t kg = (size_t)(tRowBase + skr) * 1024 + colBase + sko;
        #pragma unroll
        for (int m = 0; m < 4; ++m)
            kr[m] = *reinterpret_cast<const uint4*>(&k[kg + (size_t)m * 32 * 1024]);
        const size_t vg = (size_t)(colBase + svr) * 4096 + tRowBase + svc;
        #pragma unroll
        for (int m = 0; m < 4; ++m)
            vr[m] = *reinterpret_cast<const uint4*>(&vT[vg + (size_t)m * 16 * 4096]);
    }

    const int nkt = (qt + 2) >> 1;           // 128-key tiles
    for (int kt = 0; kt < nkt; ++kt) {
        __syncthreads();
        #pragma unroll
        for (int m = 0; m < 4; ++m) {
            *reinterpret_cast<uint4*>(&Ks[(skr + 32 * m) * LDK + sko]) = kr[m];
            *reinterpret_cast<uint4*>(&Vs[(svr + 16 * m) * LDV + svc]) = vr[m];
        }
        __syncthreads();

        if (kt + 1 < nkt) {                  // prefetch next (hidden by compute)
            const size_t kg = (size_t)(tRowBase + (kt + 1) * 128 + skr) * 1024 + colBase + sko;
            #pragma unroll
            for (int m = 0; m < 4; ++m)
                kr[m] = *reinterpret_cast<const uint4*>(&k[kg + (size_t)m * 32 * 1024]);
            const size_t vg = (size_t)(colBase + svr) * 4096 + tRowBase + (kt + 1) * 128 + svc;
            #pragma unroll
            for (int m = 0; m < 4; ++m)
                vr[m] = *reinterpret_cast<const uint4*>(&vT[vg + (size_t)m * 16 * 4096]);
        }

        // active 16-key frags this tile (block-uniform)
        const int kLim = qBase + 63 - kt * 128;
        const int nf = (kLim >= 127) ? 8 : ((kLim >> 4) + 1);
        const bool lastT = (kt == nkt - 1);

        // S = QK^T per frag; P = exp(s/8) (bounded scores), diag mask
        #pragma unroll
        for (int t = 0; t < 8; ++t) {
            if (t >= nf) continue;
            f32x4 sc = {};
            #pragma unroll
            for (int kf = 0; kf < 2; ++kf) {
                bf16x8 bk = *reinterpret_cast<const bf16x8*>(
                    &Ks[(t * 16 + l16) * LDK + kf * 32 + quad * 8]);
                sc = __builtin_amdgcn_mfma_f32_16x16x32_bf16(aq[kf], bk, sc, 0, 0, 0);
            }
            const int ki = kt * 128 + t * 16 + l16;
            #pragma unroll
            for (int r = 0; r < 4; ++r) {
                float p = __expf(sc[r] * 0.125f);
                if (lastT) {
                    const int qi = qBase + wave * 16 + quad * 4 + r;
                    if (ki > qi) p = 0.0f;
                }
                ls[r] += p;
                Ps[(wave * 16 + quad * 4 + r) * LDV + t * 16 + l16] = f2bf(p);
            }
        }
        if (nf & 1) {                        // zero-fill the pairing frag
            #pragma unroll
            for (int r = 0; r < 4; ++r)
                Ps[(wave * 16 + quad * 4 + r) * LDV + nf * 16 + l16] = 0;
        }

        // O += P @ V
        const int nkf = (nf + 1) >> 1;       // active 32-key A-frags
        #pragma unroll
        for (int kf = 0; kf < 4; ++kf) {
            if (kf >= nkf) continue;
            bf16x8 ap = *reinterpret_cast<const bf16x8*>(
                &Ps[(wave * 16 + l16) * LDV + kf * 32 + quad * 8]);
            #pragma unroll
            for (int t = 0; t < 4; ++t) {
                bf16x8 bv = *reinterpret_cast<const bf16x8*>(
                    &Vs[(t * 16 + l16) * LDV + kf * 32 + quad * 8]);
                o[t] = __builtin_amdgcn_mfma_f32_16x16x32_bf16(ap, bv, o[t], 0, 0, 0);
            }
        }
    }

    #pragma unroll
    for (int off = 1; off < 16; off <<= 1)
        #pragma unroll
        for (int r = 0; r < 4; ++r)
            ls[r] += __shfl_xor(ls[r], off);

    #pragma unroll
    for (int r = 0; r < 4; ++r) {
        const float inv = 1.0f / ls[r];
        const size_t gr = (size_t)(tRowBase + qBase + wave * 16 + quad * 4 + r) * 1024 + colBase;
        #pragma unroll
        for (int t = 0; t < 4; ++t)
            ctx[gr + t * 16 + l16] = f2bf(o[t][r] * inv);
    }
}

// ---------------------------------------------------------------------------
extern "C" void kernel_launch(void* const* d_in, const int* in_sizes, int n_in,
                              void* d_out, int out_size, void* d_ws, size_t ws_size,
                              hipStream_t stream)
{
    const float* x  = (const float*)d_in[0];   // [4096,1024] fp32
    const float* Wq = (const float*)d_in[1];
    const float* Wk = (const float*)d_in[2];
    const float* Wv = (const float*)d_in[3];
    const float* Wo = (const float*)d_in[4];
    const float* bo = (const float*)d_in[5];
    float* out = (float*)d_out;

    // ws (32 MB): xb -> ctx after gemm_qkv; kb -> woT after attn3.
    // d_out doubles as wqkvT scratch until gemm_out overwrites it.
    unsigned short* xb     = (unsigned short*)d_ws;           // 8 MB -> ctx
    unsigned short* qb     = xb + (size_t)4096 * 1024;        // 8 MB
    unsigned short* kb     = qb + (size_t)4096 * 1024;        // 8 MB -> woT
    unsigned short* vT     = kb + (size_t)4096 * 1024;        // 8 MB [1024][4096]
    unsigned short* ctx    = xb;
    unsigned short* wqkvT  = (unsigned short*)d_out;          // 6.3 MB scratch
    unsigned short* woT    = kb;

    prep<<<2816, 256, 0, stream>>>(x, xb, Wq, Wk, Wv, wqkvT);

    gemm128<0><<<dim3(24, 32), 256, 0, stream>>>(xb, wqkvT, qb, kb, vT, nullptr);

    attn3<<<dim3(32, 32), 256, 0, stream>>>(qb, kb, vT, ctx);

    wconv<<<dim3(16, 16), 256, 0, stream>>>(Wo, woT);

    gemm128<2><<<dim3(8, 32), 256, 0, stream>>>(ctx, woT, out, nullptr, nullptr, bo);
}

// Round 8
// 231.275 us; speedup vs baseline: 1.3441x; 1.3441x over previous
//
#include <hip/hip_runtime.h>

typedef __bf16 bf16x8 __attribute__((ext_vector_type(8)));
typedef float f32x4 __attribute__((ext_vector_type(4)));

__device__ inline float bf2f(unsigned short u) {
    unsigned int x = ((unsigned int)u) << 16;
    return __builtin_bit_cast(float, x);
}
__device__ inline unsigned short f2bf(float f) {
    unsigned int x = __builtin_bit_cast(unsigned int, f);
    x += 0x7fff + ((x >> 16) & 1);   // RNE; inputs finite
    return (unsigned short)(x >> 16);
}

// async global->LDS, 16B per lane; LDS dest = wave-uniform base + lane*16
__device__ __forceinline__ void gl_lds16(const unsigned short* g, unsigned short* l)
{
    __builtin_amdgcn_global_load_lds(
        (const __attribute__((address_space(1))) void*)g,
        (__attribute__((address_space(3))) void*)l, 16, 0, 0);
}

// ---------------------------------------------------------------------------
// Fused prep: blocks [0,2048): x fp32 -> xb bf16 (8 elems/thread).
// Blocks [2048,2816): Wq/Wk/Wv fp32 [k][n] -> wqkvT bf16 [n][k] (64x64 tiles).
// ---------------------------------------------------------------------------
__global__ __launch_bounds__(256)
void prep(const float* __restrict__ x, unsigned short* __restrict__ xb,
          const float* __restrict__ Wq, const float* __restrict__ Wk,
          const float* __restrict__ Wv, unsigned short* __restrict__ wT)
{
    __shared__ unsigned short T[64][72];
    if (blockIdx.x < 2048) {
        const size_t i = ((size_t)blockIdx.x * 256 + threadIdx.x) * 8;
        float4 a = *reinterpret_cast<const float4*>(x + i);
        float4 b = *reinterpret_cast<const float4*>(x + i + 4);
        unsigned short t[8] = { f2bf(a.x), f2bf(a.y), f2bf(a.z), f2bf(a.w),
                                f2bf(b.x), f2bf(b.y), f2bf(b.z), f2bf(b.w) };
        *reinterpret_cast<uint4*>(xb + i) = *reinterpret_cast<uint4*>(t);
        return;
    }
    const int blk = blockIdx.x - 2048;
    const int z = blk >> 8, within = blk & 255;
    const float* W = (z == 0) ? Wq : (z == 1) ? Wk : Wv;
    unsigned short* dstBase = wT + (size_t)z * 1024 * 1024;
    const int k0 = (within >> 4) * 64, n0 = (within & 15) * 64;
    const int r = threadIdx.x >> 2, c0 = (threadIdx.x & 3) * 16;
    const float* src = W + (size_t)(k0 + r) * 1024 + n0 + c0;
    #pragma unroll
    for (int j = 0; j < 16; j += 4) {
        float4 f = *reinterpret_cast<const float4*>(src + j);
        T[r][c0 + j]     = f2bf(f.x);
        T[r][c0 + j + 1] = f2bf(f.y);
        T[r][c0 + j + 2] = f2bf(f.z);
        T[r][c0 + j + 3] = f2bf(f.w);
    }
    __syncthreads();
    unsigned short* dst = dstBase + (size_t)(n0 + r) * 1024 + k0 + c0;
    #pragma unroll
    for (int h = 0; h < 2; ++h) {
        unsigned short t8[8];
        #pragma unroll
        for (int j = 0; j < 8; ++j) t8[j] = T[c0 + h * 8 + j][r];
        *reinterpret_cast<uint4*>(dst + h * 8) = *reinterpret_cast<uint4*>(t8);
    }
}

// ---------------------------------------------------------------------------
// Transpose-convert (Wo): fp32 [k][n] -> bf16 [n][k].
// ---------------------------------------------------------------------------
__global__ __launch_bounds__(256)
void wconv(const float* __restrict__ W, unsigned short* __restrict__ wT)
{
    __shared__ unsigned short T[64][72];
    const int k0 = blockIdx.y * 64, n0 = blockIdx.x * 64;
    const int r = threadIdx.x >> 2, c0 = (threadIdx.x & 3) * 16;
    const float* src = W + (size_t)(k0 + r) * 1024 + n0 + c0;
    #pragma unroll
    for (int j = 0; j < 16; j += 4) {
        float4 f = *reinterpret_cast<const float4*>(src + j);
        T[r][c0 + j]     = f2bf(f.x);
        T[r][c0 + j + 1] = f2bf(f.y);
        T[r][c0 + j + 2] = f2bf(f.z);
        T[r][c0 + j + 3] = f2bf(f.w);
    }
    __syncthreads();
    unsigned short* dst = wT + (size_t)(n0 + r) * 1024 + k0 + c0;
    #pragma unroll
    for (int h = 0; h < 2; ++h) {
        unsigned short t8[8];
        #pragma unroll
        for (int j = 0; j < 8; ++j) t8[j] = T[c0 + h * 8 + j][r];
        *reinterpret_cast<uint4*>(dst + h * 8) = *reinterpret_cast<uint4*>(t8);
    }
}

// ---------------------------------------------------------------------------
// m97-style GEMM: C = A[4096][1024] @ BT[N][1024]^T. 128x128 tile, BK=32,
// unpadded LDS, global_load_lds width-16 staging, 4 waves 2x2, 4x4 mfma.
// MODE 0: QKV routing (q/k normal, v transposed). MODE 2: fp32 out + bias.
// ---------------------------------------------------------------------------
template <int MODE>
__global__ __launch_bounds__(256)
void gemm128(const unsigned short* __restrict__ A,
             const unsigned short* __restrict__ BT,
             void* __restrict__ C0, void* __restrict__ C1,
             void* __restrict__ C2, const float* __restrict__ bias)
{
    __shared__ unsigned short As[128 * 32];
    __shared__ unsigned short Bs[128 * 32];

    const int tid = threadIdx.x;
    const int wave = tid >> 6, lane = tid & 63, quad = lane >> 4, l16 = lane & 15;
    const int wm = wave >> 1, wn = wave & 1;
    const int mBase = blockIdx.y * 128, nBase = blockIdx.x * 128;

    f32x4 acc[4][4] = {};

    const int srow = lane >> 2, sko = (lane & 3) * 8;

    for (int kb = 0; kb < 1024; kb += 32) {
        __syncthreads();
        #pragma unroll
        for (int j = 0; j < 2; ++j) {
            const int seg = wave * 2 + j;
            gl_lds16(A  + (size_t)(mBase + seg * 16 + srow) * 1024 + kb + sko,
                     As + seg * 512);
            gl_lds16(BT + (size_t)(nBase + seg * 16 + srow) * 1024 + kb + sko,
                     Bs + seg * 512);
        }
        __syncthreads();

        bf16x8 af[4], bf[4];
        #pragma unroll
        for (int t = 0; t < 4; ++t) {
            af[t] = *reinterpret_cast<const bf16x8*>(&As[(wm * 64 + t * 16 + l16) * 32 + quad * 8]);
            bf[t] = *reinterpret_cast<const bf16x8*>(&Bs[(wn * 64 + t * 16 + l16) * 32 + quad * 8]);
        }
        #pragma unroll
        for (int ti = 0; ti < 4; ++ti)
            #pragma unroll
            for (int tj = 0; tj < 4; ++tj)
                acc[ti][tj] = __builtin_amdgcn_mfma_f32_16x16x32_bf16(
                    af[ti], bf[tj], acc[ti][tj], 0, 0, 0);
    }

    #pragma unroll
    for (int ti = 0; ti < 4; ++ti) {
        const int row0 = mBase + wm * 64 + ti * 16 + quad * 4;
        #pragma unroll
        for (int tj = 0; tj < 4; ++tj) {
            const int col = nBase + wn * 64 + tj * 16 + l16;
            if constexpr (MODE == 0) {
                if (col < 1024) {
                    unsigned short* qb = (unsigned short*)C0;
                    #pragma unroll
                    for (int i = 0; i < 4; ++i)
                        qb[(size_t)(row0 + i) * 1024 + col] = f2bf(acc[ti][tj][i]);
                } else if (col < 2048) {
                    unsigned short* kb = (unsigned short*)C1;
                    #pragma unroll
                    for (int i = 0; i < 4; ++i)
                        kb[(size_t)(row0 + i) * 1024 + col - 1024] = f2bf(acc[ti][tj][i]);
                } else {
                    unsigned short* vT = (unsigned short*)C2;
                    unsigned short t4[4] = { f2bf(acc[ti][tj][0]), f2bf(acc[ti][tj][1]),
                                             f2bf(acc[ti][tj][2]), f2bf(acc[ti][tj][3]) };
                    *reinterpret_cast<uint2*>(&vT[(size_t)(col - 2048) * 4096 + row0]) =
                        *reinterpret_cast<uint2*>(t4);
                }
            } else {
                float* out = (float*)C0;
                const float ba = bias[col];
                #pragma unroll
                for (int i = 0; i < 4; ++i)
                    out[(size_t)(row0 + i) * 1024 + col] = acc[ti][tj][i] + ba;
            }
        }
    }
}

// ---------------------------------------------------------------------------
// MFMA causal flash attention v4: K-tile 128, global_load_lds staging (NO
// staging registers -> no spill; R7's 182 MB scratch traffic was the bug).
// LDS sub-tiles with 64-B rows (2-way bank aliasing = free):
//   Ks[2][128][32] : d-halves.  Vs[4][64][32] : key-quarters.
// 64 q-rows/block, 4 waves. No running max (scores bounded), masked P=0,
// per-lane l, one butterfly at end. Causal frag-skip on the last tile.
// ---------------------------------------------------------------------------
#define LDP 136   // Ps row stride (shorts): 272 B -> bank rotate 4/row

__global__ __launch_bounds__(256)
void attn4(const unsigned short* __restrict__ q,
           const unsigned short* __restrict__ k,
           const unsigned short* __restrict__ vT,
           unsigned short* __restrict__ ctx)
{
    __shared__ unsigned short Ks[2][128 * 32]; // [d-half][key][d%32]
    __shared__ unsigned short Vs[4][64 * 32];  // [key-qtr][d][key%32]
    __shared__ unsigned short Ps[64 * LDP];    // [qrow][key] padded

    const int tid  = threadIdx.x;
    const int wave = tid >> 6, lane = tid & 63, quad = lane >> 4, l16 = lane & 15;
    const int qt = 31 - blockIdx.x;            // longest blocks first
    const int bh = blockIdx.y;
    const int b = bh >> 4, h = bh & 15;
    const int tokBase = b * 2048;
    const int colBase = h * 64;
    const int qBase   = qt * 64;

    bf16x8 aq[2];
    {
        const unsigned short* qrow =
            q + (size_t)(tokBase + qBase + wave * 16 + l16) * 1024 + colBase;
        aq[0] = *reinterpret_cast<const bf16x8*>(qrow + quad * 8);
        aq[1] = *reinterpret_cast<const bf16x8*>(qrow + 32 + quad * 8);
    }

    f32x4 o[4] = {};
    float ls[4] = {};

    const int sa = lane >> 2;          // row-within-16 for staging
    const int sb = (lane & 3) * 8;     // 8-short column offset

    const int nkt = (qt + 2) >> 1;     // 128-key tiles
    for (int kt = 0; kt < nkt; ++kt) {
        __syncthreads();               // prior tile's LDS reads done
        const int tok0 = tokBase + kt * 128;
        // K: 2 d-halves x 2 segs per wave (16 keys x 32 shorts each)
        #pragma unroll
        for (int hh = 0; hh < 2; ++hh)
            #pragma unroll
            for (int j = 0; j < 2; ++j) {
                const int seg = wave * 2 + j;
                gl_lds16(k + (size_t)(tok0 + seg * 16 + sa) * 1024 + colBase + hh * 32 + sb,
                         &Ks[hh][seg * 512]);
            }
        // V: 4 key-quarters, 1 seg per wave (16 d-rows x 32 shorts each)
        #pragma unroll
        for (int qk = 0; qk < 4; ++qk)
            gl_lds16(vT + (size_t)(colBase + wave * 16 + sa) * 4096 + tok0 + qk * 32 + sb,
                     &Vs[qk][wave * 512]);
        __syncthreads();               // barrier drains vmcnt -> tiles visible

        // active 16-key frags this tile (block-uniform)
        const int kLim = qBase + 63 - kt * 128;
        const int nf = (kLim >= 127) ? 8 : ((kLim >> 4) + 1);
        const bool lastT = (kt == nkt - 1);

        // S = QK^T per frag; P = exp(s/8) (bounded scores), diag mask
        #pragma unroll
        for (int t = 0; t < 8; ++t) {
            if (t >= nf) continue;
            f32x4 sc = {};
            #pragma unroll
            for (int kf = 0; kf < 2; ++kf) {
                bf16x8 bk = *reinterpret_cast<const bf16x8*>(
                    &Ks[kf][(t * 16 + l16) * 32 + quad * 8]);
                sc = __builtin_amdgcn_mfma_f32_16x16x32_bf16(aq[kf], bk, sc, 0, 0, 0);
            }
            const int ki = kt * 128 + t * 16 + l16;
            #pragma unroll
            for (int r = 0; r < 4; ++r) {
                float p = __expf(sc[r] * 0.125f);
                if (lastT) {
                    const int qi = qBase + wave * 16 + quad * 4 + r;
                    if (ki > qi) p = 0.0f;
                }
                ls[r] += p;
                Ps[(wave * 16 + quad * 4 + r) * LDP + t * 16 + l16] = f2bf(p);
            }
        }
        if (nf & 1) {                  // zero-fill the pairing 16-key frag
            #pragma unroll
            for (int r = 0; r < 4; ++r)
                Ps[(wave * 16 + quad * 4 + r) * LDP + nf * 16 + l16] = 0;
        }

        // O += P @ V
        const int nkf = (nf + 1) >> 1; // active 32-key A-frags
        #pragma unroll
        for (int kf = 0; kf < 4; ++kf) {
            if (kf >= nkf) continue;
            bf16x8 ap = *reinterpret_cast<const bf16x8*>(
                &Ps[(wave * 16 + l16) * LDP + kf * 32 + quad * 8]);
            #pragma unroll
            for (int t = 0; t < 4; ++t) {
                bf16x8 bv = *reinterpret_cast<const bf16x8*>(
                    &Vs[kf][(t * 16 + l16) * 32 + quad * 8]);
                o[t] = __builtin_amdgcn_mfma_f32_16x16x32_bf16(ap, bv, o[t], 0, 0, 0);
            }
        }
    }

    #pragma unroll
    for (int off = 1; off < 16; off <<= 1)
        #pragma unroll
        for (int r = 0; r < 4; ++r)
            ls[r] += __shfl_xor(ls[r], off);

    #pragma unroll
    for (int r = 0; r < 4; ++r) {
        const float inv = 1.0f / ls[r];
        const size_t gr = (size_t)(tokBase + qBase + wave * 16 + quad * 4 + r) * 1024 + colBase;
        #pragma unroll
        for (int t = 0; t < 4; ++t)
            ctx[gr + t * 16 + l16] = f2bf(o[t][r] * inv);
    }
}

// ---------------------------------------------------------------------------
extern "C" void kernel_launch(void* const* d_in, const int* in_sizes, int n_in,
                              void* d_out, int out_size, void* d_ws, size_t ws_size,
                              hipStream_t stream)
{
    const float* x  = (const float*)d_in[0];   // [4096,1024] fp32
    const float* Wq = (const float*)d_in[1];
    const float* Wk = (const float*)d_in[2];
    const float* Wv = (const float*)d_in[3];
    const float* Wo = (const float*)d_in[4];
    const float* bo = (const float*)d_in[5];
    float* out = (float*)d_out;

    // ws (32 MB): xb -> ctx after gemm_qkv; kb -> woT after attn4.
    // d_out doubles as wqkvT scratch until gemm_out overwrites it.
    unsigned short* xb     = (unsigned short*)d_ws;           // 8 MB -> ctx
    unsigned short* qb     = xb + (size_t)4096 * 1024;        // 8 MB
    unsigned short* kb     = qb + (size_t)4096 * 1024;        // 8 MB -> woT
    unsigned short* vT     = kb + (size_t)4096 * 1024;        // 8 MB [1024][4096]
    unsigned short* ctx    = xb;
    unsigned short* wqkvT  = (unsigned short*)d_out;          // 6.3 MB scratch
    unsigned short* woT    = kb;

    prep<<<2816, 256, 0, stream>>>(x, xb, Wq, Wk, Wv, wqkvT);

    gemm128<0><<<dim3(24, 32), 256, 0, stream>>>(xb, wqkvT, qb, kb, vT, nullptr);

    attn4<<<dim3(32, 32), 256, 0, stream>>>(qb, kb, vT, ctx);

    wconv<<<dim3(16, 16), 256, 0, stream>>>(Wo, woT);

    gemm128<2><<<dim3(8, 32), 256, 0, stream>>>(ctx, woT, out, nullptr, nullptr, bo);
}

// Round 9
// 225.962 us; speedup vs baseline: 1.3757x; 1.0235x over previous
//
#include <hip/hip_runtime.h>

typedef __bf16 bf16x8 __attribute__((ext_vector_type(8)));
typedef float f32x4 __attribute__((ext_vector_type(4)));

__device__ inline float bf2f(unsigned short u) {
    unsigned int x = ((unsigned int)u) << 16;
    return __builtin_bit_cast(float, x);
}
__device__ inline unsigned short f2bf(float f) {
    unsigned int x = __builtin_bit_cast(unsigned int, f);
    x += 0x7fff + ((x >> 16) & 1);   // RNE; inputs finite
    return (unsigned short)(x >> 16);
}

// async global->LDS, 16B per lane; LDS dest = wave-uniform base + lane*16
__device__ __forceinline__ void gl_lds16(const unsigned short* g, unsigned short* l)
{
    __builtin_amdgcn_global_load_lds(
        (const __attribute__((address_space(1))) void*)g,
        (__attribute__((address_space(3))) void*)l, 16, 0, 0);
}

// ---------------------------------------------------------------------------
// Fused prep: blocks [0,2048): x fp32 -> xb bf16 (8 elems/thread).
// Blocks [2048,2816): Wq/Wk/Wv fp32 [k][n] -> wqkvT bf16 [n][k] (64x64 tiles).
// ---------------------------------------------------------------------------
__global__ __launch_bounds__(256)
void prep(const float* __restrict__ x, unsigned short* __restrict__ xb,
          const float* __restrict__ Wq, const float* __restrict__ Wk,
          const float* __restrict__ Wv, unsigned short* __restrict__ wT)
{
    __shared__ unsigned short T[64][72];
    if (blockIdx.x < 2048) {
        const size_t i = ((size_t)blockIdx.x * 256 + threadIdx.x) * 8;
        float4 a = *reinterpret_cast<const float4*>(x + i);
        float4 b = *reinterpret_cast<const float4*>(x + i + 4);
        unsigned short t[8] = { f2bf(a.x), f2bf(a.y), f2bf(a.z), f2bf(a.w),
                                f2bf(b.x), f2bf(b.y), f2bf(b.z), f2bf(b.w) };
        *reinterpret_cast<uint4*>(xb + i) = *reinterpret_cast<uint4*>(t);
        return;
    }
    const int blk = blockIdx.x - 2048;
    const int z = blk >> 8, within = blk & 255;
    const float* W = (z == 0) ? Wq : (z == 1) ? Wk : Wv;
    unsigned short* dstBase = wT + (size_t)z * 1024 * 1024;
    const int k0 = (within >> 4) * 64, n0 = (within & 15) * 64;
    const int r = threadIdx.x >> 2, c0 = (threadIdx.x & 3) * 16;
    const float* src = W + (size_t)(k0 + r) * 1024 + n0 + c0;
    #pragma unroll
    for (int j = 0; j < 16; j += 4) {
        float4 f = *reinterpret_cast<const float4*>(src + j);
        T[r][c0 + j]     = f2bf(f.x);
        T[r][c0 + j + 1] = f2bf(f.y);
        T[r][c0 + j + 2] = f2bf(f.z);
        T[r][c0 + j + 3] = f2bf(f.w);
    }
    __syncthreads();
    unsigned short* dst = dstBase + (size_t)(n0 + r) * 1024 + k0 + c0;
    #pragma unroll
    for (int h = 0; h < 2; ++h) {
        unsigned short t8[8];
        #pragma unroll
        for (int j = 0; j < 8; ++j) t8[j] = T[c0 + h * 8 + j][r];
        *reinterpret_cast<uint4*>(dst + h * 8) = *reinterpret_cast<uint4*>(t8);
    }
}

// ---------------------------------------------------------------------------
// Transpose-convert (Wo): fp32 [k][n] -> bf16 [n][k].
// ---------------------------------------------------------------------------
__global__ __launch_bounds__(256)
void wconv(const float* __restrict__ W, unsigned short* __restrict__ wT)
{
    __shared__ unsigned short T[64][72];
    const int k0 = blockIdx.y * 64, n0 = blockIdx.x * 64;
    const int r = threadIdx.x >> 2, c0 = (threadIdx.x & 3) * 16;
    const float* src = W + (size_t)(k0 + r) * 1024 + n0 + c0;
    #pragma unroll
    for (int j = 0; j < 16; j += 4) {
        float4 f = *reinterpret_cast<const float4*>(src + j);
        T[r][c0 + j]     = f2bf(f.x);
        T[r][c0 + j + 1] = f2bf(f.y);
        T[r][c0 + j + 2] = f2bf(f.z);
        T[r][c0 + j + 3] = f2bf(f.w);
    }
    __syncthreads();
    unsigned short* dst = wT + (size_t)(n0 + r) * 1024 + k0 + c0;
    #pragma unroll
    for (int h = 0; h < 2; ++h) {
        unsigned short t8[8];
        #pragma unroll
        for (int j = 0; j < 8; ++j) t8[j] = T[c0 + h * 8 + j][r];
        *reinterpret_cast<uint4*>(dst + h * 8) = *reinterpret_cast<uint4*>(t8);
    }
}

// ---------------------------------------------------------------------------
// m97-style GEMM: C = A[4096][1024] @ BT[N][1024]^T. 128x128 tile, BK=32,
// unpadded LDS, global_load_lds width-16 staging, 4 waves 2x2, 4x4 mfma.
// MODE 0: QKV routing (q/k normal, v transposed). MODE 2: fp32 out + bias.
// ---------------------------------------------------------------------------
template <int MODE>
__global__ __launch_bounds__(256)
void gemm128(const unsigned short* __restrict__ A,
             const unsigned short* __restrict__ BT,
             void* __restrict__ C0, void* __restrict__ C1,
             void* __restrict__ C2, const float* __restrict__ bias)
{
    __shared__ unsigned short As[128 * 32];
    __shared__ unsigned short Bs[128 * 32];

    const int tid = threadIdx.x;
    const int wave = tid >> 6, lane = tid & 63, quad = lane >> 4, l16 = lane & 15;
    const int wm = wave >> 1, wn = wave & 1;
    const int mBase = blockIdx.y * 128, nBase = blockIdx.x * 128;

    f32x4 acc[4][4] = {};

    const int srow = lane >> 2, sko = (lane & 3) * 8;

    for (int kb = 0; kb < 1024; kb += 32) {
        __syncthreads();
        #pragma unroll
        for (int j = 0; j < 2; ++j) {
            const int seg = wave * 2 + j;
            gl_lds16(A  + (size_t)(mBase + seg * 16 + srow) * 1024 + kb + sko,
                     As + seg * 512);
            gl_lds16(BT + (size_t)(nBase + seg * 16 + srow) * 1024 + kb + sko,
                     Bs + seg * 512);
        }
        __syncthreads();

        bf16x8 af[4], bf[4];
        #pragma unroll
        for (int t = 0; t < 4; ++t) {
            af[t] = *reinterpret_cast<const bf16x8*>(&As[(wm * 64 + t * 16 + l16) * 32 + quad * 8]);
            bf[t] = *reinterpret_cast<const bf16x8*>(&Bs[(wn * 64 + t * 16 + l16) * 32 + quad * 8]);
        }
        #pragma unroll
        for (int ti = 0; ti < 4; ++ti)
            #pragma unroll
            for (int tj = 0; tj < 4; ++tj)
                acc[ti][tj] = __builtin_amdgcn_mfma_f32_16x16x32_bf16(
                    af[ti], bf[tj], acc[ti][tj], 0, 0, 0);
    }

    #pragma unroll
    for (int ti = 0; ti < 4; ++ti) {
        const int row0 = mBase + wm * 64 + ti * 16 + quad * 4;
        #pragma unroll
        for (int tj = 0; tj < 4; ++tj) {
            const int col = nBase + wn * 64 + tj * 16 + l16;
            if constexpr (MODE == 0) {
                if (col < 1024) {
                    unsigned short* qb = (unsigned short*)C0;
                    #pragma unroll
                    for (int i = 0; i < 4; ++i)
                        qb[(size_t)(row0 + i) * 1024 + col] = f2bf(acc[ti][tj][i]);
                } else if (col < 2048) {
                    unsigned short* kb = (unsigned short*)C1;
                    #pragma unroll
                    for (int i = 0; i < 4; ++i)
                        kb[(size_t)(row0 + i) * 1024 + col - 1024] = f2bf(acc[ti][tj][i]);
                } else {
                    unsigned short* vT = (unsigned short*)C2;
                    unsigned short t4[4] = { f2bf(acc[ti][tj][0]), f2bf(acc[ti][tj][1]),
                                             f2bf(acc[ti][tj][2]), f2bf(acc[ti][tj][3]) };
                    *reinterpret_cast<uint2*>(&vT[(size_t)(col - 2048) * 4096 + row0]) =
                        *reinterpret_cast<uint2*>(t4);
                }
            } else {
                float* out = (float*)C0;
                const float ba = bias[col];
                #pragma unroll
                for (int i = 0; i < 4; ++i)
                    out[(size_t)(row0 + i) * 1024 + col] = acc[ti][tj][i] + ba;
            }
        }
    }
}

// ---------------------------------------------------------------------------
// MFMA causal flash attention v5: K-tile 64, gl_lds staging into DOUBLE-
// buffered LDS, ONE barrier per tile-iter: prefetch for kt+1 is issued at
// the top (async DMA, no VGPRs), compute runs on buf[kt&1], the single
// end-of-iter barrier drains the prefetch -- latency hidden behind compute.
// WAR on buf^1 guarded by the previous iter's barrier. Sub-tiles with 64-B
// rows (2-way bank aliasing = free): Ks[buf][dhalf][64key x 32], V from
// vT as Vs[buf][keyhalf][64d x 32]. No running max (scores bounded),
// masked P=0, per-lane l, one butterfly at end. Wave-uniform PV frag skip
// on the diagonal tile.
// ---------------------------------------------------------------------------
#define LDP 72    // Ps row stride (shorts), 16B-aligned rows

__global__ __launch_bounds__(256)
void attn5(const unsigned short* __restrict__ q,
           const unsigned short* __restrict__ k,
           const unsigned short* __restrict__ vT,
           unsigned short* __restrict__ ctx)
{
    __shared__ unsigned short Ks[2][2][64 * 32]; // [buf][d-half][key][d%32]
    __shared__ unsigned short Vs[2][2][64 * 32]; // [buf][key-half][d][key%32]
    __shared__ unsigned short Ps[64 * LDP];      // [qrow][key]

    const int tid  = threadIdx.x;
    const int wave = tid >> 6, lane = tid & 63, quad = lane >> 4, l16 = lane & 15;
    const int qt = 31 - blockIdx.x;              // longest blocks first
    const int bh = blockIdx.y;
    const int b = bh >> 4, h = bh & 15;
    const int tokBase = b * 2048;
    const int colBase = h * 64;
    const int qBase   = qt * 64;

    bf16x8 aq[2];
    {
        const unsigned short* qrow =
            q + (size_t)(tokBase + qBase + wave * 16 + l16) * 1024 + colBase;
        aq[0] = *reinterpret_cast<const bf16x8*>(qrow + quad * 8);
        aq[1] = *reinterpret_cast<const bf16x8*>(qrow + 32 + quad * 8);
    }

    f32x4 o[4] = {};
    float ls[4] = {};

    const int sa = lane >> 2;            // staging row-within-16
    const int sb = (lane & 3) * 8;       // staging 8-short col offset

    // Stage one 64-key tile into buffer `buf`. 4 gl_lds per wave:
    // ops o=0,1 -> (half hh = op>>2, rowgrp rg = op&3) for K and V alike.
    auto stage = [&](int tok0, int buf) {
        #pragma unroll
        for (int o = 0; o < 2; ++o) {
            const int op = wave * 2 + o;
            const int hh = op >> 2, rg = op & 3;
            gl_lds16(k + (size_t)(tok0 + rg * 16 + sa) * 1024 + colBase + hh * 32 + sb,
                     &Ks[buf][hh][rg * 16 * 32]);
            gl_lds16(vT + (size_t)(colBase + rg * 16 + sa) * 4096 + tok0 + hh * 32 + sb,
                     &Vs[buf][hh][rg * 16 * 32]);
        }
    };

    stage(tokBase, 0);
    __syncthreads();                     // drains tile-0 DMA

    const int nkt = qt + 1;              // 64-key tiles
    for (int kt = 0; kt < nkt; ++kt) {
        const int buf = kt & 1;
        if (kt + 1 < nkt)
            stage(tokBase + (kt + 1) * 64, buf ^ 1);   // async, lands by barrier

        // S = QK^T (16x64 per wave)
        f32x4 sc[4] = {};
        #pragma unroll
        for (int t = 0; t < 4; ++t)
            #pragma unroll
            for (int kf = 0; kf < 2; ++kf) {
                bf16x8 bk = *reinterpret_cast<const bf16x8*>(
                    &Ks[buf][kf][(t * 16 + l16) * 32 + quad * 8]);
                sc[t] = __builtin_amdgcn_mfma_f32_16x16x32_bf16(aq[kf], bk, sc[t], 0, 0, 0);
            }

        // P = exp(s/8) (bounded scores: no running max), diag mask -> 0
        const bool diag = (kt == qt);
        #pragma unroll
        for (int t = 0; t < 4; ++t) {
            const int ki = kt * 64 + t * 16 + l16;
            #pragma unroll
            for (int r = 0; r < 4; ++r) {
                float p = __expf(sc[t][r] * 0.125f);
                if (diag) {
                    const int qi = qBase + wave * 16 + quad * 4 + r;
                    if (ki > qi) p = 0.0f;
                }
                ls[r] += p;
                Ps[(wave * 16 + quad * 4 + r) * LDP + t * 16 + l16] = f2bf(p);
            }
        }

        // O += P @ V  (skip wave-uniformly fully-masked 32-key frags on diag)
        #pragma unroll
        for (int kf = 0; kf < 2; ++kf) {
            if (diag && (wave * 16 + 15) < kf * 32) continue;
            bf16x8 ap = *reinterpret_cast<const bf16x8*>(
                &Ps[(wave * 16 + l16) * LDP + kf * 32 + quad * 8]);
            #pragma unroll
            for (int t = 0; t < 4; ++t) {
                bf16x8 bv = *reinterpret_cast<const bf16x8*>(
                    &Vs[buf][kf][(t * 16 + l16) * 32 + quad * 8]);
                o[t] = __builtin_amdgcn_mfma_f32_16x16x32_bf16(ap, bv, o[t], 0, 0, 0);
            }
        }

        if (kt + 1 < nkt)
            __syncthreads();             // drains prefetch; guards buffer swap
    }

    #pragma unroll
    for (int off = 1; off < 16; off <<= 1)
        #pragma unroll
        for (int r = 0; r < 4; ++r)
            ls[r] += __shfl_xor(ls[r], off);

    #pragma unroll
    for (int r = 0; r < 4; ++r) {
        const float inv = 1.0f / ls[r];
        const size_t gr = (size_t)(tokBase + qBase + wave * 16 + quad * 4 + r) * 1024 + colBase;
        #pragma unroll
        for (int t = 0; t < 4; ++t)
            ctx[gr + t * 16 + l16] = f2bf(o[t][r] * inv);
    }
}

// ---------------------------------------------------------------------------
extern "C" void kernel_launch(void* const* d_in, const int* in_sizes, int n_in,
                              void* d_out, int out_size, void* d_ws, size_t ws_size,
                              hipStream_t stream)
{
    const float* x  = (const float*)d_in[0];   // [4096,1024] fp32
    const float* Wq = (const float*)d_in[1];
    const float* Wk = (const float*)d_in[2];
    const float* Wv = (const float*)d_in[3];
    const float* Wo = (const float*)d_in[4];
    const float* bo = (const float*)d_in[5];
    float* out = (float*)d_out;

    // ws (32 MB): xb -> ctx after gemm_qkv; kb -> woT after attn5.
    // d_out doubles as wqkvT scratch until gemm_out overwrites it.
    unsigned short* xb     = (unsigned short*)d_ws;           // 8 MB -> ctx
    unsigned short* qb     = xb + (size_t)4096 * 1024;        // 8 MB
    unsigned short* kb     = qb + (size_t)4096 * 1024;        // 8 MB -> woT
    unsigned short* vT     = kb + (size_t)4096 * 1024;        // 8 MB [1024][4096]
    unsigned short* ctx    = xb;
    unsigned short* wqkvT  = (unsigned short*)d_out;          // 6.3 MB scratch
    unsigned short* woT    = kb;

    prep<<<2816, 256, 0, stream>>>(x, xb, Wq, Wk, Wv, wqkvT);

    gemm128<0><<<dim3(24, 32), 256, 0, stream>>>(xb, wqkvT, qb, kb, vT, nullptr);

    attn5<<<dim3(32, 32), 256, 0, stream>>>(qb, kb, vT, ctx);

    wconv<<<dim3(16, 16), 256, 0, stream>>>(Wo, woT);

    gemm128<2><<<dim3(8, 32), 256, 0, stream>>>(ctx, woT, out, nullptr, nullptr, bo);
}

// Round 10
// 194.396 us; speedup vs baseline: 1.5991x; 1.1624x over previous
//
#include <hip/hip_runtime.h>

typedef __bf16 bf16x8 __attribute__((ext_vector_type(8)));
typedef float f32x4 __attribute__((ext_vector_type(4)));

__device__ inline float bf2f(unsigned short u) {
    unsigned int x = ((unsigned int)u) << 16;
    return __builtin_bit_cast(float, x);
}
__device__ inline unsigned short f2bf(float f) {
    unsigned int x = __builtin_bit_cast(unsigned int, f);
    x += 0x7fff + ((x >> 16) & 1);   // RNE; inputs finite
    return (unsigned short)(x >> 16);
}

// async global->LDS, 16B per lane; LDS dest = wave-uniform base + lane*16
__device__ __forceinline__ void gl_lds16(const unsigned short* g, unsigned short* l)
{
    __builtin_amdgcn_global_load_lds(
        (const __attribute__((address_space(1))) void*)g,
        (__attribute__((address_space(3))) void*)l, 16, 0, 0);
}

// ---------------------------------------------------------------------------
// Fused prep: blocks [0,2048): x fp32 -> xb bf16 (8 elems/thread).
// Blocks [2048,2816): Wq/Wk/Wv fp32 [k][n] -> wqkvT bf16 [n][k] (64x64 tiles).
// ---------------------------------------------------------------------------
__global__ __launch_bounds__(256)
void prep(const float* __restrict__ x, unsigned short* __restrict__ xb,
          const float* __restrict__ Wq, const float* __restrict__ Wk,
          const float* __restrict__ Wv, unsigned short* __restrict__ wT)
{
    __shared__ unsigned short T[64][72];
    if (blockIdx.x < 2048) {
        const size_t i = ((size_t)blockIdx.x * 256 + threadIdx.x) * 8;
        float4 a = *reinterpret_cast<const float4*>(x + i);
        float4 b = *reinterpret_cast<const float4*>(x + i + 4);
        unsigned short t[8] = { f2bf(a.x), f2bf(a.y), f2bf(a.z), f2bf(a.w),
                                f2bf(b.x), f2bf(b.y), f2bf(b.z), f2bf(b.w) };
        *reinterpret_cast<uint4*>(xb + i) = *reinterpret_cast<uint4*>(t);
        return;
    }
    const int blk = blockIdx.x - 2048;
    const int z = blk >> 8, within = blk & 255;
    const float* W = (z == 0) ? Wq : (z == 1) ? Wk : Wv;
    unsigned short* dstBase = wT + (size_t)z * 1024 * 1024;
    const int k0 = (within >> 4) * 64, n0 = (within & 15) * 64;
    const int r = threadIdx.x >> 2, c0 = (threadIdx.x & 3) * 16;
    const float* src = W + (size_t)(k0 + r) * 1024 + n0 + c0;
    #pragma unroll
    for (int j = 0; j < 16; j += 4) {
        float4 f = *reinterpret_cast<const float4*>(src + j);
        T[r][c0 + j]     = f2bf(f.x);
        T[r][c0 + j + 1] = f2bf(f.y);
        T[r][c0 + j + 2] = f2bf(f.z);
        T[r][c0 + j + 3] = f2bf(f.w);
    }
    __syncthreads();
    unsigned short* dst = dstBase + (size_t)(n0 + r) * 1024 + k0 + c0;
    #pragma unroll
    for (int h = 0; h < 2; ++h) {
        unsigned short t8[8];
        #pragma unroll
        for (int j = 0; j < 8; ++j) t8[j] = T[c0 + h * 8 + j][r];
        *reinterpret_cast<uint4*>(dst + h * 8) = *reinterpret_cast<uint4*>(t8);
    }
}

// ---------------------------------------------------------------------------
// Transpose-convert (Wo): fp32 [k][n] -> bf16 [n][k].
// ---------------------------------------------------------------------------
__global__ __launch_bounds__(256)
void wconv(const float* __restrict__ W, unsigned short* __restrict__ wT)
{
    __shared__ unsigned short T[64][72];
    const int k0 = blockIdx.y * 64, n0 = blockIdx.x * 64;
    const int r = threadIdx.x >> 2, c0 = (threadIdx.x & 3) * 16;
    const float* src = W + (size_t)(k0 + r) * 1024 + n0 + c0;
    #pragma unroll
    for (int j = 0; j < 16; j += 4) {
        float4 f = *reinterpret_cast<const float4*>(src + j);
        T[r][c0 + j]     = f2bf(f.x);
        T[r][c0 + j + 1] = f2bf(f.y);
        T[r][c0 + j + 2] = f2bf(f.z);
        T[r][c0 + j + 3] = f2bf(f.w);
    }
    __syncthreads();
    unsigned short* dst = wT + (size_t)(n0 + r) * 1024 + k0 + c0;
    #pragma unroll
    for (int h = 0; h < 2; ++h) {
        unsigned short t8[8];
        #pragma unroll
        for (int j = 0; j < 8; ++j) t8[j] = T[c0 + h * 8 + j][r];
        *reinterpret_cast<uint4*>(dst + h * 8) = *reinterpret_cast<uint4*>(t8);
    }
}

// ---------------------------------------------------------------------------
// m97-style GEMM: C = A[4096][1024] @ BT[N][1024]^T. 128x128 tile, BK=32,
// unpadded LDS, global_load_lds width-16 staging, 4 waves 2x2, 4x4 mfma.
// MODE 0: QKV routing (q/k normal, v transposed). MODE 2: fp32 out + bias.
// ---------------------------------------------------------------------------
template <int MODE>
__global__ __launch_bounds__(256)
void gemm128(const unsigned short* __restrict__ A,
             const unsigned short* __restrict__ BT,
             void* __restrict__ C0, void* __restrict__ C1,
             void* __restrict__ C2, const float* __restrict__ bias)
{
    __shared__ unsigned short As[128 * 32];
    __shared__ unsigned short Bs[128 * 32];

    const int tid = threadIdx.x;
    const int wave = tid >> 6, lane = tid & 63, quad = lane >> 4, l16 = lane & 15;
    const int wm = wave >> 1, wn = wave & 1;
    const int mBase = blockIdx.y * 128, nBase = blockIdx.x * 128;

    f32x4 acc[4][4] = {};

    const int srow = lane >> 2, sko = (lane & 3) * 8;

    for (int kb = 0; kb < 1024; kb += 32) {
        __syncthreads();
        #pragma unroll
        for (int j = 0; j < 2; ++j) {
            const int seg = wave * 2 + j;
            gl_lds16(A  + (size_t)(mBase + seg * 16 + srow) * 1024 + kb + sko,
                     As + seg * 512);
            gl_lds16(BT + (size_t)(nBase + seg * 16 + srow) * 1024 + kb + sko,
                     Bs + seg * 512);
        }
        __syncthreads();

        bf16x8 af[4], bf[4];
        #pragma unroll
        for (int t = 0; t < 4; ++t) {
            af[t] = *reinterpret_cast<const bf16x8*>(&As[(wm * 64 + t * 16 + l16) * 32 + quad * 8]);
            bf[t] = *reinterpret_cast<const bf16x8*>(&Bs[(wn * 64 + t * 16 + l16) * 32 + quad * 8]);
        }
        #pragma unroll
        for (int ti = 0; ti < 4; ++ti)
            #pragma unroll
            for (int tj = 0; tj < 4; ++tj)
                acc[ti][tj] = __builtin_amdgcn_mfma_f32_16x16x32_bf16(
                    af[ti], bf[tj], acc[ti][tj], 0, 0, 0);
    }

    #pragma unroll
    for (int ti = 0; ti < 4; ++ti) {
        const int row0 = mBase + wm * 64 + ti * 16 + quad * 4;
        #pragma unroll
        for (int tj = 0; tj < 4; ++tj) {
            const int col = nBase + wn * 64 + tj * 16 + l16;
            if constexpr (MODE == 0) {
                if (col < 1024) {
                    unsigned short* qb = (unsigned short*)C0;
                    #pragma unroll
                    for (int i = 0; i < 4; ++i)
                        qb[(size_t)(row0 + i) * 1024 + col] = f2bf(acc[ti][tj][i]);
                } else if (col < 2048) {
                    unsigned short* kb = (unsigned short*)C1;
                    #pragma unroll
                    for (int i = 0; i < 4; ++i)
                        kb[(size_t)(row0 + i) * 1024 + col - 1024] = f2bf(acc[ti][tj][i]);
                } else {
                    unsigned short* vT = (unsigned short*)C2;
                    unsigned short t4[4] = { f2bf(acc[ti][tj][0]), f2bf(acc[ti][tj][1]),
                                             f2bf(acc[ti][tj][2]), f2bf(acc[ti][tj][3]) };
                    *reinterpret_cast<uint2*>(&vT[(size_t)(col - 2048) * 4096 + row0]) =
                        *reinterpret_cast<uint2*>(t4);
                }
            } else {
                float* out = (float*)C0;
                const float ba = bias[col];
                #pragma unroll
                for (int i = 0; i < 4; ++i)
                    out[(size_t)(row0 + i) * 1024 + col] = acc[ti][tj][i] + ba;
            }
        }
    }
}

// ---------------------------------------------------------------------------
// MFMA causal flash attention v6: BALANCED triangle folding. Block j (0..15)
// per (b,h) owns q-tile pair (31-j, j): every block does exactly 33
// (q,k)-tile pairs -> 512 equal blocks, no skew tail (attn2/4/5's real
// limiter: time-avg occupancy ~13% from work skew). Tile B's k-range is a
// subset of tile A's, so one staged K/V tile feeds both q-tiles on shared
// iters (staging -26%, 2x compute per barrier to hide the prefetch DMA).
// Structure from attn5: gl_lds dbuf staging, 1 barrier/iter, no running
// max (scores bounded), masked P=0, per-lane l, butterfly at end.
// ---------------------------------------------------------------------------
#define LDP 72    // Ps row stride (shorts), 16B-aligned rows

__global__ __launch_bounds__(256)
void attn6(const unsigned short* __restrict__ q,
           const unsigned short* __restrict__ k,
           const unsigned short* __restrict__ vT,
           unsigned short* __restrict__ ctx)
{
    __shared__ unsigned short Ks[2][2][64 * 32]; // [buf][d-half][key][d%32]
    __shared__ unsigned short Vs[2][2][64 * 32]; // [buf][key-half][d][key%32]
    __shared__ unsigned short PsA[64 * LDP];
    __shared__ unsigned short PsB[64 * LDP];

    const int tid  = threadIdx.x;
    const int wave = tid >> 6, lane = tid & 63, quad = lane >> 4, l16 = lane & 15;
    const int j  = blockIdx.x;               // 0..15 pair index
    const int bh = blockIdx.y;
    const int b = bh >> 4, h = bh & 15;
    const int tokBase = b * 2048;
    const int colBase = h * 64;
    const int qtA = 31 - j, qtB = j;
    const int qBaseA = qtA * 64, qBaseB = qtB * 64;

    bf16x8 aqA[2], aqB[2];
    {
        const unsigned short* qrA =
            q + (size_t)(tokBase + qBaseA + wave * 16 + l16) * 1024 + colBase;
        aqA[0] = *reinterpret_cast<const bf16x8*>(qrA + quad * 8);
        aqA[1] = *reinterpret_cast<const bf16x8*>(qrA + 32 + quad * 8);
        const unsigned short* qrB =
            q + (size_t)(tokBase + qBaseB + wave * 16 + l16) * 1024 + colBase;
        aqB[0] = *reinterpret_cast<const bf16x8*>(qrB + quad * 8);
        aqB[1] = *reinterpret_cast<const bf16x8*>(qrB + 32 + quad * 8);
    }

    f32x4 oA[4] = {}, oB[4] = {};
    float lsA[4] = {}, lsB[4] = {};

    const int sa = lane >> 2;            // staging row-within-16
    const int sb = (lane & 3) * 8;       // staging 8-short col offset

    auto stage = [&](int tok0, int buf) {
        #pragma unroll
        for (int o = 0; o < 2; ++o) {
            const int op = wave * 2 + o;
            const int hh = op >> 2, rg = op & 3;
            gl_lds16(k + (size_t)(tok0 + rg * 16 + sa) * 1024 + colBase + hh * 32 + sb,
                     &Ks[buf][hh][rg * 16 * 32]);
            gl_lds16(vT + (size_t)(colBase + rg * 16 + sa) * 4096 + tok0 + hh * 32 + sb,
                     &Vs[buf][hh][rg * 16 * 32]);
        }
    };

    stage(tokBase, 0);
    __syncthreads();                     // drains tile-0 DMA

    const int nkt = qtA + 1;             // 64-key tiles (tile A's range)
    for (int kt = 0; kt < nkt; ++kt) {
        const int buf = kt & 1;
        if (kt + 1 < nkt)
            stage(tokBase + (kt + 1) * 64, buf ^ 1);   // async, lands by barrier

        const bool doB = (kt <= qtB);
        const bool diagA = (kt == qtA), diagB = (kt == qtB);

        // ---- QK^T + softmax, tile A
        {
            f32x4 sc[4] = {};
            #pragma unroll
            for (int t = 0; t < 4; ++t)
                #pragma unroll
                for (int kf = 0; kf < 2; ++kf) {
                    bf16x8 bk = *reinterpret_cast<const bf16x8*>(
                        &Ks[buf][kf][(t * 16 + l16) * 32 + quad * 8]);
                    sc[t] = __builtin_amdgcn_mfma_f32_16x16x32_bf16(aqA[kf], bk, sc[t], 0, 0, 0);
                }
            #pragma unroll
            for (int t = 0; t < 4; ++t) {
                const int ki = kt * 64 + t * 16 + l16;
                #pragma unroll
                for (int r = 0; r < 4; ++r) {
                    float p = __expf(sc[t][r] * 0.125f);
                    if (diagA && ki > qBaseA + wave * 16 + quad * 4 + r) p = 0.0f;
                    lsA[r] += p;
                    PsA[(wave * 16 + quad * 4 + r) * LDP + t * 16 + l16] = f2bf(p);
                }
            }
        }
        // ---- QK^T + softmax, tile B (shared k-tile)
        if (doB) {
            f32x4 sc[4] = {};
            #pragma unroll
            for (int t = 0; t < 4; ++t)
                #pragma unroll
                for (int kf = 0; kf < 2; ++kf) {
                    bf16x8 bk = *reinterpret_cast<const bf16x8*>(
                        &Ks[buf][kf][(t * 16 + l16) * 32 + quad * 8]);
                    sc[t] = __builtin_amdgcn_mfma_f32_16x16x32_bf16(aqB[kf], bk, sc[t], 0, 0, 0);
                }
            #pragma unroll
            for (int t = 0; t < 4; ++t) {
                const int ki = kt * 64 + t * 16 + l16;
                #pragma unroll
                for (int r = 0; r < 4; ++r) {
                    float p = __expf(sc[t][r] * 0.125f);
                    if (diagB && ki > qBaseB + wave * 16 + quad * 4 + r) p = 0.0f;
                    lsB[r] += p;
                    PsB[(wave * 16 + quad * 4 + r) * LDP + t * 16 + l16] = f2bf(p);
                }
            }
        }

        // ---- O += P @ V (wave-uniform skip of fully-masked frags on diag)
        #pragma unroll
        for (int kf = 0; kf < 2; ++kf) {
            if (diagA && (wave * 16 + 15) < kf * 32) continue;
            bf16x8 ap = *reinterpret_cast<const bf16x8*>(
                &PsA[(wave * 16 + l16) * LDP + kf * 32 + quad * 8]);
            #pragma unroll
            for (int t = 0; t < 4; ++t) {
                bf16x8 bv = *reinterpret_cast<const bf16x8*>(
                    &Vs[buf][kf][(t * 16 + l16) * 32 + quad * 8]);
                oA[t] = __builtin_amdgcn_mfma_f32_16x16x32_bf16(ap, bv, oA[t], 0, 0, 0);
            }
        }
        if (doB) {
            #pragma unroll
            for (int kf = 0; kf < 2; ++kf) {
                if (diagB && (wave * 16 + 15) < kf * 32) continue;
                bf16x8 ap = *reinterpret_cast<const bf16x8*>(
                    &PsB[(wave * 16 + l16) * LDP + kf * 32 + quad * 8]);
                #pragma unroll
                for (int t = 0; t < 4; ++t) {
                    bf16x8 bv = *reinterpret_cast<const bf16x8*>(
                        &Vs[buf][kf][(t * 16 + l16) * 32 + quad * 8]);
                    oB[t] = __builtin_amdgcn_mfma_f32_16x16x32_bf16(ap, bv, oB[t], 0, 0, 0);
                }
            }
        }

        if (kt + 1 < nkt)
            __syncthreads();             // drains prefetch; guards buffer swap
    }

    #pragma unroll
    for (int off = 1; off < 16; off <<= 1)
        #pragma unroll
        for (int r = 0; r < 4; ++r) {
            lsA[r] += __shfl_xor(lsA[r], off);
            lsB[r] += __shfl_xor(lsB[r], off);
        }

    #pragma unroll
    for (int r = 0; r < 4; ++r) {
        const float invA = 1.0f / lsA[r];
        const float invB = 1.0f / lsB[r];
        const size_t grA = (size_t)(tokBase + qBaseA + wave * 16 + quad * 4 + r) * 1024 + colBase;
        const size_t grB = (size_t)(tokBase + qBaseB + wave * 16 + quad * 4 + r) * 1024 + colBase;
        #pragma unroll
        for (int t = 0; t < 4; ++t) {
            ctx[grA + t * 16 + l16] = f2bf(oA[t][r] * invA);
            ctx[grB + t * 16 + l16] = f2bf(oB[t][r] * invB);
        }
    }
}

// ---------------------------------------------------------------------------
extern "C" void kernel_launch(void* const* d_in, const int* in_sizes, int n_in,
                              void* d_out, int out_size, void* d_ws, size_t ws_size,
                              hipStream_t stream)
{
    const float* x  = (const float*)d_in[0];   // [4096,1024] fp32
    const float* Wq = (const float*)d_in[1];
    const float* Wk = (const float*)d_in[2];
    const float* Wv = (const float*)d_in[3];
    const float* Wo = (const float*)d_in[4];
    const float* bo = (const float*)d_in[5];
    float* out = (float*)d_out;

    // ws (32 MB): xb -> ctx after gemm_qkv; kb -> woT after attn6.
    // d_out doubles as wqkvT scratch until gemm_out overwrites it.
    unsigned short* xb     = (unsigned short*)d_ws;           // 8 MB -> ctx
    unsigned short* qb     = xb + (size_t)4096 * 1024;        // 8 MB
    unsigned short* kb     = qb + (size_t)4096 * 1024;        // 8 MB -> woT
    unsigned short* vT     = kb + (size_t)4096 * 1024;        // 8 MB [1024][4096]
    unsigned short* ctx    = xb;
    unsigned short* wqkvT  = (unsigned short*)d_out;          // 6.3 MB scratch
    unsigned short* woT    = kb;

    prep<<<2816, 256, 0, stream>>>(x, xb, Wq, Wk, Wv, wqkvT);

    gemm128<0><<<dim3(24, 32), 256, 0, stream>>>(xb, wqkvT, qb, kb, vT, nullptr);

    attn6<<<dim3(16, 32), 256, 0, stream>>>(qb, kb, vT, ctx);

    wconv<<<dim3(16, 16), 256, 0, stream>>>(Wo, woT);

    gemm128<2><<<dim3(8, 32), 256, 0, stream>>>(ctx, woT, out, nullptr, nullptr, bo);
}